// Round 4
// baseline (113.387 us; speedup 1.0000x reference)
//
#include <hip/hip_runtime.h>
#include <hip/hip_bf16.h>

#define NPTS 16384
#define NNBR 32
#define CIN 16
#define COUT 16
#define NBASIS 16

__device__ __forceinline__ float us2f(unsigned short u) {
    union { unsigned int i; float f; } c; c.i = ((unsigned int)u) << 16; return c.f;
}
__device__ __forceinline__ unsigned short f2us_trunc(float f) {
    union { float f; unsigned int i; } c; c.f = f; return (unsigned short)(c.i >> 16);
}

// One kernel, no workspace. 256 threads = 16 points x 16 lanes. 1024 blocks.
__global__ __launch_bounds__(256) void se3_conv_kernel(
        const float* __restrict__ input,     // (CIN, NPTS) f32 (bf16-rounded values)
        const float* __restrict__ coords,    // (NPTS, 3)   f32
        const float* __restrict__ W,         // (COUT, CIN, NBASIS) f32
        const float* __restrict__ centers,   // (NBASIS,)   f32
        const float* __restrict__ mask,      // (NPTS, NNBR) f32
        const int* __restrict__ neighbors,   // (NPTS, NNBR) int32
        float* __restrict__ out) {           // (COUT, NPTS) f32
    // LDS budget (static limit 64 KB):
    //   Wt   4096 ushort = 8 KB    (bf16-truncated bits; harness data is
    //                               bf16-rounded f32, so truncation is lossless)
    //   rbfm 16*513 f32  = 32.8 KB (stride 513: 513%32==1, the 4 point-groups
    //                               of a wave land on distinct banks)
    //   Mld  16*257 f32  = 16.4 KB (stride 257, same reasoning)
    //   nbrs 16*33  int  = 2.1 KB
    //   total ~58.3 KB -> 2 blocks/CU, 8 waves/CU.
    __shared__ unsigned short Wt[COUT * CIN * NBASIS]; // [ib][o]
    __shared__ float rbfm[16 * 513];                   // [p][k*16+b]
    __shared__ float Mld[16 * 257];                    // [p][i*16+b]
    __shared__ int   nbrs[16 * 33];                    // [p][k]
    __shared__ float cent[NBASIS];

    const int tid = threadIdx.x;
    const int p = tid >> 4;    // point within block (0..15)
    const int t = tid & 15;    // lane role within point-group (0..15)
    const int n = blockIdx.x * 16 + p;

    // Stage W transposed: Wt[(i*16+b)*16 + o] = W[o][i][b]. Coalesced f32 reads.
    for (int idx = tid; idx < COUT * CIN * NBASIS; idx += 256) {
        int o = idx >> 8;        // 0..15
        int ib = idx & 255;      // i*16+b
        Wt[ib * 16 + o] = f2us_trunc(W[idx]);
    }
    if (tid < NBASIS) cent[tid] = centers[tid];
    __syncthreads();

    // ---- Phase A: mask * rbf into LDS. Each lane handles k = t and t+16.
    const float cx = coords[n * 3 + 0];
    const float cy = coords[n * 3 + 1];
    const float cz = coords[n * 3 + 2];
    #pragma unroll
    for (int kk = 0; kk < 2; ++kk) {
        const int k = t + kk * 16;
        const int nbr = neighbors[n * NNBR + k] & (NPTS - 1);  // OOB insurance
        nbrs[p * 33 + k] = nbr;
        const float dx = coords[nbr * 3 + 0] - cx;
        const float dy = coords[nbr * 3 + 1] - cy;
        const float dz = coords[nbr * 3 + 2] - cz;
        const float r = sqrtf(dx * dx + dy * dy + dz * dz + 1e-12f);
        const float m = mask[n * NNBR + k];
        float* rb = &rbfm[p * 513 + k * 16];
        #pragma unroll
        for (int b = 0; b < NBASIS; ++b) {
            const float d = r - cent[b];
            rb[b] = m * __expf(-10.0f * d * d);
        }
    }
    __syncthreads();

    // ---- Phase B: lane t == input channel i.
    // M[i][b] = sum_k input[i, nbr_k] * rbfm[k][b]
    float acc[NBASIS];
    #pragma unroll
    for (int b = 0; b < NBASIS; ++b) acc[b] = 0.0f;
    #pragma unroll 4
    for (int k = 0; k < NNBR; ++k) {
        const int nbr = nbrs[p * 33 + k];
        const float x = input[t * NPTS + nbr];         // L2-resident scalar load
        const float* rb = &rbfm[p * 513 + k * 16];     // broadcast within group
        #pragma unroll
        for (int b = 0; b < NBASIS; ++b) acc[b] += x * rb[b];
    }
    #pragma unroll
    for (int b = 0; b < NBASIS; ++b) Mld[p * 257 + t * 16 + b] = acc[b];
    __syncthreads();

    // ---- Phase C: lane t == output channel o.
    // out[o,n] = sum_{ib} Wt[ib][o] * M[ib]
    float s = 0.0f;
    #pragma unroll 8
    for (int ib = 0; ib < CIN * NBASIS; ++ib) {
        s += us2f(Wt[ib * 16 + t]) * Mld[p * 257 + ib];
    }
    out[t * NPTS + n] = s;
}

extern "C" void kernel_launch(void* const* d_in, const int* in_sizes, int n_in,
                              void* d_out, int out_size, void* d_ws, size_t ws_size,
                              hipStream_t stream) {
    const float* input   = (const float*)d_in[0];
    const float* coords  = (const float*)d_in[1];
    const float* W       = (const float*)d_in[2];
    const float* centers = (const float*)d_in[3];
    const float* mask    = (const float*)d_in[4];
    const int*   nbr     = (const int*)d_in[5];
    float* out = (float*)d_out;

    se3_conv_kernel<<<NPTS / 16, 256, 0, stream>>>(input, coords, W, centers,
                                                   mask, nbr, out);
}

// Round 5
// 102.942 us; speedup vs baseline: 1.1015x; 1.1015x over previous
//
#include <hip/hip_runtime.h>
#include <hip/hip_bf16.h>

#define NPTS 16384
#define NNBR 32
#define CIN 16
#define COUT 16
#define NBASIS 16

#define WT_ISTRIDE 24                 // ushorts per i-row (16 + 8 pad): 48 B, 12 dw -> 2-way banks (free)
#define WT_OSTRIDE (16 * WT_ISTRIDE)  // 384 ushorts per o-row
#define RB_PSTRIDE 520                // ushorts per point (32*16 + 8 pad): 1040 B = 260 dw == 4 mod 32

__device__ __forceinline__ unsigned short f2us_rn(float f) {  // f32 -> bf16 bits, RTN
    union { float f; unsigned int i; } c; c.f = f;
    unsigned int x = c.i + 0x7fffu + ((c.i >> 16) & 1u);
    return (unsigned short)(x >> 16);
}
__device__ __forceinline__ float blo(unsigned int u) {   // low bf16 of packed pair
    union { unsigned int i; float f; } c; c.i = u << 16; return c.f;
}
__device__ __forceinline__ float bhi(unsigned int u) {   // high bf16 of packed pair
    union { unsigned int i; float f; } c; c.i = u & 0xffff0000u; return c.f;
}

// 256 threads = 16 points x 16 lanes. 1024 blocks (whole grid co-resident:
// 31 KB LDS -> 5 blocks/CU capacity, 4 blocks/CU resident, 16 waves/CU).
__global__ __launch_bounds__(256) void se3_conv_kernel(
        const float* __restrict__ input,     // (CIN, NPTS)
        const float* __restrict__ coords,    // (NPTS, 3)
        const float* __restrict__ W,         // (COUT, CIN, NBASIS)
        const float* __restrict__ centers,   // (NBASIS,)
        const float* __restrict__ mask,      // (NPTS, NNBR)
        const int* __restrict__ neighbors,   // (NPTS, NNBR)
        float* __restrict__ out) {           // (COUT, NPTS)
    // LDS ~31 KB total:
    //   Wt  bf16 [o][i][b], i-stride 24 us  -> 12.0 KB, reads 2-way (free)
    //   rbp bf16 [p][k][b], p-stride 520 us -> 16.3 KB, group reads 16-bank-disjoint
    //   nbrs int [p][k], stride 33          ->  2.1 KB, broadcast reads
    __shared__ __align__(16) unsigned short Wt[16 * WT_OSTRIDE];
    __shared__ __align__(16) unsigned short rbp[16 * RB_PSTRIDE];
    __shared__ int nbrs[16 * 33];

    const int tid = threadIdx.x;
    const int p = tid >> 4;    // point within block
    const int t = tid & 15;    // lane role: k-half producer (A), channel i (B/C)
    const int n = blockIdx.x * 16 + p;

    // centers -> registers (uniform address; scalarizes to s_load)
    float cent[NBASIS];
    #pragma unroll
    for (int b = 0; b < NBASIS; ++b) cent[b] = centers[b];

    // Stage W as bf16, layout [o][i*24 + b]. Coalesced reads, conflict-free writes.
    for (int idx = tid; idx < COUT * CIN * NBASIS; idx += 256) {
        int o = idx >> 8, i = (idx >> 4) & 15, b = idx & 15;
        Wt[o * WT_OSTRIDE + i * WT_ISTRIDE + b] = f2us_rn(W[idx]);
    }

    // ---- Phase A: mask * rbf -> packed bf16 in LDS. Lane t does k = t, t+16.
    const float cx = coords[n * 3 + 0];
    const float cy = coords[n * 3 + 1];
    const float cz = coords[n * 3 + 2];
    #pragma unroll
    for (int kk = 0; kk < 2; ++kk) {
        const int k = t + kk * 16;
        const int nbr = neighbors[n * NNBR + k] & (NPTS - 1);
        nbrs[p * 33 + k] = nbr;
        const float dx = coords[nbr * 3 + 0] - cx;
        const float dy = coords[nbr * 3 + 1] - cy;
        const float dz = coords[nbr * 3 + 2] - cz;
        const float r = sqrtf(dx * dx + dy * dy + dz * dz + 1e-12f);
        const float m = mask[n * NNBR + k];
        unsigned int pk[8];
        #pragma unroll
        for (int b2 = 0; b2 < 8; ++b2) {
            const float d0 = r - cent[2 * b2];
            const float d1 = r - cent[2 * b2 + 1];
            const float f0 = m * __expf(-10.0f * d0 * d0);
            const float f1 = m * __expf(-10.0f * d1 * d1);
            pk[b2] = (unsigned int)f2us_rn(f0) | ((unsigned int)f2us_rn(f1) << 16);
        }
        uint4* dst = (uint4*)&rbp[p * RB_PSTRIDE + k * 16];
        dst[0] = make_uint4(pk[0], pk[1], pk[2], pk[3]);
        dst[1] = make_uint4(pk[4], pk[5], pk[6], pk[7]);
    }
    // rbp/nbrs are produced and consumed within the same wave (16-lane groups
    // never span waves) -> ordered by lgkmcnt. Barrier only for cross-wave Wt.
    __syncthreads();

    // ---- Phase B: lane t == input channel i. acc[b] = M[i][b] in registers.
    float acc[NBASIS];
    #pragma unroll
    for (int b = 0; b < NBASIS; ++b) acc[b] = 0.0f;
    #pragma unroll 4
    for (int k = 0; k < NNBR; ++k) {
        const int nbr = nbrs[p * 33 + k];
        const float x = input[t * NPTS + nbr];     // L2-resident gather
        const uint4* rq = (const uint4*)&rbp[p * RB_PSTRIDE + k * 16];
        const uint4 q0 = rq[0];
        const uint4 q1 = rq[1];
        acc[ 0] += x * blo(q0.x);  acc[ 1] += x * bhi(q0.x);
        acc[ 2] += x * blo(q0.y);  acc[ 3] += x * bhi(q0.y);
        acc[ 4] += x * blo(q0.z);  acc[ 5] += x * bhi(q0.z);
        acc[ 6] += x * blo(q0.w);  acc[ 7] += x * bhi(q0.w);
        acc[ 8] += x * blo(q1.x);  acc[ 9] += x * bhi(q1.x);
        acc[10] += x * blo(q1.y);  acc[11] += x * bhi(q1.y);
        acc[12] += x * blo(q1.z);  acc[13] += x * bhi(q1.z);
        acc[14] += x * blo(q1.w);  acc[15] += x * bhi(q1.w);
    }

    // ---- Phase C (fused): per o, dot(W[o,i,:], acc) then xor-reduce over i.
    float outv = 0.0f;
    #pragma unroll 4
    for (int o = 0; o < COUT; ++o) {
        const uint4* wq = (const uint4*)&Wt[o * WT_OSTRIDE + t * WT_ISTRIDE];
        const uint4 w0 = wq[0];
        const uint4 w1 = wq[1];
        float dot;
        dot  = acc[ 0] * blo(w0.x) + acc[ 1] * bhi(w0.x);
        dot += acc[ 2] * blo(w0.y) + acc[ 3] * bhi(w0.y);
        dot += acc[ 4] * blo(w0.z) + acc[ 5] * bhi(w0.z);
        dot += acc[ 6] * blo(w0.w) + acc[ 7] * bhi(w0.w);
        dot += acc[ 8] * blo(w1.x) + acc[ 9] * bhi(w1.x);
        dot += acc[10] * blo(w1.y) + acc[11] * bhi(w1.y);
        dot += acc[12] * blo(w1.z) + acc[13] * bhi(w1.z);
        dot += acc[14] * blo(w1.w) + acc[15] * bhi(w1.w);
        dot += __shfl_xor(dot, 1);
        dot += __shfl_xor(dot, 2);
        dot += __shfl_xor(dot, 4);
        dot += __shfl_xor(dot, 8);
        outv = (o == t) ? dot : outv;
    }
    out[t * NPTS + n] = outv;
}

extern "C" void kernel_launch(void* const* d_in, const int* in_sizes, int n_in,
                              void* d_out, int out_size, void* d_ws, size_t ws_size,
                              hipStream_t stream) {
    const float* input   = (const float*)d_in[0];
    const float* coords  = (const float*)d_in[1];
    const float* W       = (const float*)d_in[2];
    const float* centers = (const float*)d_in[3];
    const float* mask    = (const float*)d_in[4];
    const int*   nbr     = (const int*)d_in[5];
    float* out = (float*)d_out;

    se3_conv_kernel<<<NPTS / 16, 256, 0, stream>>>(input, coords, W, centers,
                                                   mask, nbr, out);
}

// Round 6
// 87.727 us; speedup vs baseline: 1.2925x; 1.1734x over previous
//
#include <hip/hip_runtime.h>
#include <hip/hip_bf16.h>

#define NPTS 16384
#define NNBR 32
#define CIN 16
#define COUT 16
#define NBASIS 16

#define WT_ISTRIDE 24                 // ushorts per i-row (16 + 8 pad)
#define WT_OSTRIDE (16 * WT_ISTRIDE)  // 384 ushorts per o-row
#define RB_PSTRIDE 520                // ushorts per point (32*16 + 8 pad)

__device__ __forceinline__ unsigned short f2us_rn(float f) {  // f32 -> bf16 bits, RTN
    union { float f; unsigned int i; } c; c.f = f;
    unsigned int x = c.i + 0x7fffu + ((c.i >> 16) & 1u);
    return (unsigned short)(x >> 16);
}
__device__ __forceinline__ float blo(unsigned int u) {
    union { unsigned int i; float f; } c; c.i = u << 16; return c.f;
}
__device__ __forceinline__ float bhi(unsigned int u) {
    union { unsigned int i; float f; } c; c.i = u & 0xffff0000u; return c.f;
}

// Transpose input (CIN, NPTS) -> xT (NPTS, CIN), both f32. Fully coalesced:
// reads stride-1 along n per channel; writes 64 B contiguous per lane (4x float4).
__global__ __launch_bounds__(256) void transpose_kernel(
        const float* __restrict__ input, float* __restrict__ xT) {
    const int n = blockIdx.x * 256 + threadIdx.x;
    float v[CIN];
    #pragma unroll
    for (int i = 0; i < CIN; ++i) v[i] = input[i * NPTS + n];
    float4* dst = (float4*)&xT[n * CIN];
    #pragma unroll
    for (int j = 0; j < 4; ++j)
        dst[j] = make_float4(v[4 * j], v[4 * j + 1], v[4 * j + 2], v[4 * j + 3]);
}

// 256 threads = 16 points x 16 lanes. 1024 blocks. LDS ~31 KB -> 4 blocks/CU
// resident (whole grid in one shot), 16 waves/CU.
// USE_XT: gather from transposed xT (64 B contiguous per point-group) instead
// of the 64 KB-strided raw input (64-line scatter per wave instruction).
template <bool USE_XT>
__global__ __launch_bounds__(256) void se3_conv_kernel(
        const float* __restrict__ input,     // (CIN, NPTS)
        const float* __restrict__ xT,        // (NPTS, CIN) or null
        const float* __restrict__ coords,    // (NPTS, 3)
        const float* __restrict__ W,         // (COUT, CIN, NBASIS)
        const float* __restrict__ centers,   // (NBASIS,)
        const float* __restrict__ mask,      // (NPTS, NNBR)
        const int* __restrict__ neighbors,   // (NPTS, NNBR)
        float* __restrict__ out) {           // (COUT, NPTS)
    __shared__ __align__(16) unsigned short Wt[16 * WT_OSTRIDE]; // 12.0 KB
    __shared__ __align__(16) unsigned short rbp[16 * RB_PSTRIDE];// 16.3 KB
    __shared__ int nbrs[16 * 33];                                //  2.1 KB

    const int tid = threadIdx.x;
    const int p = tid >> 4;    // point within block
    const int t = tid & 15;    // lane role: k-half (A), channel i (B/C)
    const int n = blockIdx.x * 16 + p;

    float cent[NBASIS];
    #pragma unroll
    for (int b = 0; b < NBASIS; ++b) cent[b] = centers[b];

    // Stage W as bf16, layout [o][i*24 + b].
    for (int idx = tid; idx < COUT * CIN * NBASIS; idx += 256) {
        int o = idx >> 8, i = (idx >> 4) & 15, b = idx & 15;
        Wt[o * WT_OSTRIDE + i * WT_ISTRIDE + b] = f2us_rn(W[idx]);
    }

    // ---- Phase A: mask * rbf -> packed bf16 in LDS. Lane t does k = t, t+16.
    const float cx = coords[n * 3 + 0];
    const float cy = coords[n * 3 + 1];
    const float cz = coords[n * 3 + 2];
    #pragma unroll
    for (int kk = 0; kk < 2; ++kk) {
        const int k = t + kk * 16;
        const int nbr = neighbors[n * NNBR + k] & (NPTS - 1);
        nbrs[p * 33 + k] = nbr;
        const float dx = coords[nbr * 3 + 0] - cx;
        const float dy = coords[nbr * 3 + 1] - cy;
        const float dz = coords[nbr * 3 + 2] - cz;
        const float r = sqrtf(dx * dx + dy * dy + dz * dz + 1e-12f);
        const float m = mask[n * NNBR + k];
        unsigned int pk[8];
        #pragma unroll
        for (int b2 = 0; b2 < 8; ++b2) {
            const float d0 = r - cent[2 * b2];
            const float d1 = r - cent[2 * b2 + 1];
            const float f0 = m * __expf(-10.0f * d0 * d0);
            const float f1 = m * __expf(-10.0f * d1 * d1);
            pk[b2] = (unsigned int)f2us_rn(f0) | ((unsigned int)f2us_rn(f1) << 16);
        }
        uint4* dst = (uint4*)&rbp[p * RB_PSTRIDE + k * 16];
        dst[0] = make_uint4(pk[0], pk[1], pk[2], pk[3]);
        dst[1] = make_uint4(pk[4], pk[5], pk[6], pk[7]);
    }
    // rbp/nbrs RAW is intra-wave (16-lane groups never span waves) -> lgkmcnt
    // ordering suffices; barrier is for cross-wave Wt staging only.
    __syncthreads();

    // ---- Phase B: lane t == input channel i. acc[b] = M[i][b] in registers.
    float acc[NBASIS];
    #pragma unroll
    for (int b = 0; b < NBASIS; ++b) acc[b] = 0.0f;
    #pragma unroll 8
    for (int k = 0; k < NNBR; ++k) {
        const int nbr = nbrs[p * 33 + k];
        // USE_XT: 16 lanes of a group read one contiguous 64 B segment.
        const float x = USE_XT ? xT[nbr * CIN + t] : input[t * NPTS + nbr];
        const uint4* rq = (const uint4*)&rbp[p * RB_PSTRIDE + k * 16];
        const uint4 q0 = rq[0];
        const uint4 q1 = rq[1];
        acc[ 0] += x * blo(q0.x);  acc[ 1] += x * bhi(q0.x);
        acc[ 2] += x * blo(q0.y);  acc[ 3] += x * bhi(q0.y);
        acc[ 4] += x * blo(q0.z);  acc[ 5] += x * bhi(q0.z);
        acc[ 6] += x * blo(q0.w);  acc[ 7] += x * bhi(q0.w);
        acc[ 8] += x * blo(q1.x);  acc[ 9] += x * bhi(q1.x);
        acc[10] += x * blo(q1.y);  acc[11] += x * bhi(q1.y);
        acc[12] += x * blo(q1.z);  acc[13] += x * bhi(q1.z);
        acc[14] += x * blo(q1.w);  acc[15] += x * bhi(q1.w);
    }

    // ---- Phase C (fused): per o, dot(W[o,i,:], acc), xor-reduce over i-lanes.
    float outv = 0.0f;
    #pragma unroll 4
    for (int o = 0; o < COUT; ++o) {
        const uint4* wq = (const uint4*)&Wt[o * WT_OSTRIDE + t * WT_ISTRIDE];
        const uint4 w0 = wq[0];
        const uint4 w1 = wq[1];
        float dot;
        dot  = acc[ 0] * blo(w0.x) + acc[ 1] * bhi(w0.x);
        dot += acc[ 2] * blo(w0.y) + acc[ 3] * bhi(w0.y);
        dot += acc[ 4] * blo(w0.z) + acc[ 5] * bhi(w0.z);
        dot += acc[ 6] * blo(w0.w) + acc[ 7] * bhi(w0.w);
        dot += acc[ 8] * blo(w1.x) + acc[ 9] * bhi(w1.x);
        dot += acc[10] * blo(w1.y) + acc[11] * bhi(w1.y);
        dot += acc[12] * blo(w1.z) + acc[13] * bhi(w1.z);
        dot += acc[14] * blo(w1.w) + acc[15] * bhi(w1.w);
        dot += __shfl_xor(dot, 1);
        dot += __shfl_xor(dot, 2);
        dot += __shfl_xor(dot, 4);
        dot += __shfl_xor(dot, 8);
        outv = (o == t) ? dot : outv;
    }
    out[t * NPTS + n] = outv;
}

extern "C" void kernel_launch(void* const* d_in, const int* in_sizes, int n_in,
                              void* d_out, int out_size, void* d_ws, size_t ws_size,
                              hipStream_t stream) {
    const float* input   = (const float*)d_in[0];
    const float* coords  = (const float*)d_in[1];
    const float* W       = (const float*)d_in[2];
    const float* centers = (const float*)d_in[3];
    const float* mask    = (const float*)d_in[4];
    const int*   nbr     = (const int*)d_in[5];
    float* out = (float*)d_out;

    const size_t xt_bytes = (size_t)NPTS * CIN * sizeof(float);  // 1 MB
    if (ws_size >= xt_bytes) {   // constant across calls -> graph-capture safe
        float* xT = (float*)d_ws;
        transpose_kernel<<<NPTS / 256, 256, 0, stream>>>(input, xT);
        se3_conv_kernel<true><<<NPTS / 16, 256, 0, stream>>>(
            input, xT, coords, W, centers, mask, nbr, out);
    } else {
        se3_conv_kernel<false><<<NPTS / 16, 256, 0, stream>>>(
            input, nullptr, coords, W, centers, mask, nbr, out);
    }
}

// Round 7
// 76.864 us; speedup vs baseline: 1.4752x; 1.1413x over previous
//
#include <hip/hip_runtime.h>
#include <hip/hip_bf16.h>

#define NPTS 16384
#define NNBR 32
#define CIN 16
#define COUT 16
#define NBASIS 16

// LDS layouts (f16 units):
//   Wf  [o][bi]  bi = b*16+i, row stride 264 (528 B, 16B-aligned, 2-way banks)
//   RT  [pt][b][k] b-row stride 40 (80 B), per-point stride 648 (1296 B)
//   Mld [pt][bi]  row stride 264
#define WF_OS 264
#define RT_BS 40
#define RT_PS 648
#define ML_PS 264

typedef _Float16 half8 __attribute__((ext_vector_type(8)));
typedef float floatx4 __attribute__((ext_vector_type(4)));

// Transpose input (CIN, NPTS) -> xT (NPTS, CIN) f32. Fully coalesced.
__global__ __launch_bounds__(256) void transpose_kernel(
        const float* __restrict__ input, float* __restrict__ xT) {
    const int n = blockIdx.x * 256 + threadIdx.x;
    float v[CIN];
    #pragma unroll
    for (int i = 0; i < CIN; ++i) v[i] = input[i * NPTS + n];
    float4* dst = (float4*)&xT[n * CIN];
    #pragma unroll
    for (int j = 0; j < 4; ++j)
        dst[j] = make_float4(v[4 * j], v[4 * j + 1], v[4 * j + 2], v[4 * j + 3]);
}

// 256 threads = 16 points. Wave w owns points 4w..4w+3 (one mfma_16x16x32 each
// for M = X*R), then wave 0 does Out = W*Mflat as 8 chained MFMAs for all 16
// points. LDS 37.6 KB -> 4 blocks/CU.
__global__ __launch_bounds__(256) void se3_conv_kernel(
        const float* __restrict__ xT,        // (NPTS, CIN)
        const float* __restrict__ coords,    // (NPTS, 3)
        const float* __restrict__ W,         // (COUT, CIN, NBASIS)
        const float* __restrict__ centers,   // (NBASIS,)
        const float* __restrict__ mask,      // (NPTS, NNBR)
        const int* __restrict__ neighbors,   // (NPTS, NNBR)
        float* __restrict__ out) {           // (COUT, NPTS)
    __shared__ _Float16 Wf[COUT * WF_OS];    // 8448 B
    __shared__ _Float16 RT[16 * RT_PS];      // 20736 B
    __shared__ _Float16 Mld[16 * ML_PS];     // 8448 B

    const int tid = threadIdx.x;
    const int p = tid >> 4;          // point-in-block this lane produces rbf for
    const int t = tid & 15;          // lane role
    const int quad = (tid >> 4) & 3; // quad within wave
    const int wv = tid >> 6;         // wave index (0..3)
    const int nbase = blockIdx.x * 16;

    float cent[NBASIS];
    #pragma unroll
    for (int b = 0; b < NBASIS; ++b) cent[b] = centers[b];

    // Stage W transposed to bi = b*16+i ordering: Wf[o][b*16+i] = W[o][i][b].
    for (int idx = tid; idx < COUT * CIN * NBASIS; idx += 256) {
        int o = idx >> 8, i = (idx >> 4) & 15, b = idx & 15;
        Wf[o * WF_OS + b * 16 + i] = (_Float16)W[idx];
    }

    // ---- Phase A: rbf (no mask) -> RT[p][b][k], lane t does k = t, t+16.
    {
        const int n = nbase + p;
        const float cx = coords[n * 3 + 0];
        const float cy = coords[n * 3 + 1];
        const float cz = coords[n * 3 + 2];
        #pragma unroll
        for (int kk = 0; kk < 2; ++kk) {
            const int k = t + kk * 16;
            const int nbr = neighbors[n * NNBR + k] & (NPTS - 1);
            const float dx = coords[nbr * 3 + 0] - cx;
            const float dy = coords[nbr * 3 + 1] - cy;
            const float dz = coords[nbr * 3 + 2] - cz;
            const float r = sqrtf(dx * dx + dy * dy + dz * dz + 1e-12f);
            #pragma unroll
            for (int b = 0; b < NBASIS; ++b) {
                const float d = r - cent[b];
                RT[p * RT_PS + b * RT_BS + k] = (_Float16)__expf(-10.0f * d * d);
            }
        }
    }
    __syncthreads();   // covers Wf staging + cross-check RT (RT is intra-wave)

    // ---- Phase B: per owned point q: M = X * R via one mfma_f32_16x16x32_f16.
    // A-frag: A[m=i=t][k=8*quad+j] = xT[nbr_k][i] * mask[k]  (f16)
    // B-frag: B[k=8*quad+j][n=b=t] = RT[q][b][k]             (1 ds_read_b128)
    // C-frag: lane holds M[i=t... no: D[row=4*quad+v][col=t] = M[i-row? ]
    //   D[m][n] with m=i, n=b: lane holds M[i=4*quad+v][b=t] -> Mld bi=b*16+i
    //   write 4 contiguous f16 at bi = t*16 + 4*quad + v  (one b64).
    #pragma unroll
    for (int q = 0; q < 4; ++q) {
        const int pq = wv * 4 + q;          // point-in-block
        const int n = nbase + pq;
        // neighbor indices + mask for k = 8*quad .. 8*quad+7 (contiguous loads)
        int nb[8];
        float mv[8];
        const int kbase = 8 * quad;
        #pragma unroll
        for (int j = 0; j < 8; ++j) {
            nb[j] = neighbors[n * NNBR + kbase + j] & (NPTS - 1);
            mv[j] = mask[n * NNBR + kbase + j];
        }
        half8 afrag;
        #pragma unroll
        for (int j = 0; j < 8; ++j) {
            const float x = xT[nb[j] * CIN + t];   // 64 B segment per 16 lanes
            afrag[j] = (_Float16)(x * mv[j]);
        }
        const half8 bfrag = *(const half8*)&RT[pq * RT_PS + t * RT_BS + kbase];
        floatx4 c = {0.0f, 0.0f, 0.0f, 0.0f};
        c = __builtin_amdgcn_mfma_f32_16x16x32_f16(afrag, bfrag, c, 0, 0, 0);
        // store M to Mld in bi-order (contiguous in v)
        _Float16 h[4];
        #pragma unroll
        for (int v = 0; v < 4; ++v) h[v] = (_Float16)c[v];
        *(uint2*)&Mld[pq * ML_PS + t * 16 + 4 * quad] = *(uint2*)h;
    }
    __syncthreads();   // Mld produced by all waves, consumed by wave 0

    // ---- Phase C (wave 0): Out[o][pt] = sum_bi W[o][bi] * Mflat[bi][pt],
    // 8 chained MFMAs over bi. A[m=o=t][bi-chunk], B[bi-chunk][n=pt=t].
    if (tid < 64) {
        floatx4 acc = {0.0f, 0.0f, 0.0f, 0.0f};
        #pragma unroll
        for (int cch = 0; cch < 8; ++cch) {
            const int bi = cch * 32 + 8 * quad;
            const half8 a = *(const half8*)&Wf[t * WF_OS + bi];
            const half8 b = *(const half8*)&Mld[t * ML_PS + bi];
            acc = __builtin_amdgcn_mfma_f32_16x16x32_f16(a, b, acc, 0, 0, 0);
        }
        // D[row=o=4*quad+v][col=pt=t]
        #pragma unroll
        for (int v = 0; v < 4; ++v) {
            out[(4 * quad + v) * NPTS + nbase + t] = acc[v];
        }
    }
}

extern "C" void kernel_launch(void* const* d_in, const int* in_sizes, int n_in,
                              void* d_out, int out_size, void* d_ws, size_t ws_size,
                              hipStream_t stream) {
    const float* input   = (const float*)d_in[0];
    const float* coords  = (const float*)d_in[1];
    const float* W       = (const float*)d_in[2];
    const float* centers = (const float*)d_in[3];
    const float* mask    = (const float*)d_in[4];
    const int*   nbr     = (const int*)d_in[5];
    float* out = (float*)d_out;

    float* xT = (float*)d_ws;   // 1 MB (ws is 256 MB per R6 fill counters)
    transpose_kernel<<<NPTS / 256, 256, 0, stream>>>(input, xT);
    se3_conv_kernel<<<NPTS / 16, 256, 0, stream>>>(xT, coords, W, centers,
                                                   mask, nbr, out);
}

// Round 8
// 75.770 us; speedup vs baseline: 1.4965x; 1.0144x over previous
//
#include <hip/hip_runtime.h>
#include <hip/hip_bf16.h>

#define NPTS 16384
#define NNBR 32
#define CIN 16
#define COUT 16
#define NBASIS 16

// LDS layouts (f16 units): row stride 264 (528 B) -> lane stride 132 dw = 4
// banks mod 32 -> 2-way aliasing on b128 reads (free, m136).
#define WF_OS 264
#define ML_PS 264

typedef _Float16 half8 __attribute__((ext_vector_type(8)));
typedef unsigned short ushort8 __attribute__((ext_vector_type(8)));
typedef float floatx4 __attribute__((ext_vector_type(4)));

// Transpose input (CIN, NPTS) -> xT (NPTS, CIN) f32. Fully coalesced.
__global__ __launch_bounds__(256) void transpose_kernel(
        const float* __restrict__ input, float* __restrict__ xT) {
    const int n = blockIdx.x * 256 + threadIdx.x;
    float v[CIN];
    #pragma unroll
    for (int i = 0; i < CIN; ++i) v[i] = input[i * NPTS + n];
    float4* dst = (float4*)&xT[n * CIN];
    #pragma unroll
    for (int j = 0; j < 4; ++j)
        dst[j] = make_float4(v[4 * j], v[4 * j + 1], v[4 * j + 2], v[4 * j + 3]);
}

// 256 threads = 16 points, 1024 blocks. Per wave: 4 points (B: 1 MFMA each),
// then C for all 16 points on EVERY wave (redundant 8 MFMAs, each wave stores
// its quarter of the columns). rbf never round-trips LDS: Phase A stores only
// r / nbr(u16) / mask(f16); Phase B lanes compute exp directly in B-frag
// layout (b = lane, each (pt,k,b) computed exactly once).
__global__ __launch_bounds__(256) void se3_conv_kernel(
        const float* __restrict__ xT,        // (NPTS, CIN)
        const float* __restrict__ coords,    // (NPTS, 3)
        const float* __restrict__ W,         // (COUT, CIN, NBASIS)
        const float* __restrict__ centers,   // (NBASIS,)
        const float* __restrict__ mask,      // (NPTS, NNBR)
        const int* __restrict__ neighbors,   // (NPTS, NNBR)
        float* __restrict__ out) {           // (COUT, NPTS)
    __shared__ _Float16 Wf[COUT * WF_OS];        // 8448 B  [o][b*16+i]
    __shared__ _Float16 Mld[16 * ML_PS];         // 8448 B  [pt][b*16+i]
    __shared__ float    rs[16 * NNBR];           // 2048 B  [pt][k]
    __shared__ unsigned short nb16[16 * NNBR];   // 1024 B  [pt][k]
    __shared__ _Float16 mv16[16 * NNBR];         // 1024 B  [pt][k]

    const int tid = threadIdx.x;
    const int t = tid & 15;          // lane role (i / b / o / pt by phase)
    const int quad = (tid >> 4) & 3; // quad within wave
    const int wv = tid >> 6;         // wave (0..3)
    const int nbase = blockIdx.x * 16;

    // Stage W: thread (o = tid>>4, b = tid&15) writes 16 contiguous f16
    // (Wf[o][b*16 + i]) as two b128s. Reads stride-16 (W is 16 KB, L2-hot).
    {
        const int o = tid >> 4, b = tid & 15;
        _Float16 wrow[16];
        #pragma unroll
        for (int i = 0; i < CIN; ++i)
            wrow[i] = (_Float16)W[o * 256 + i * 16 + b];
        *(half8*)&Wf[o * WF_OS + b * 16]     = *(half8*)&wrow[0];
        *(half8*)&Wf[o * WF_OS + b * 16 + 8] = *(half8*)&wrow[8];
    }

    // ---- Phase A: r, nbr, mask for all (pt, k) pairs. Coalesced everything.
    #pragma unroll
    for (int s = 0; s < 2; ++s) {
        const int f = tid + s * 256;        // pt*32 + k
        const int pt = f >> 5;
        const int n = nbase + pt;
        const int nbr = neighbors[nbase * NNBR + f] & (NPTS - 1);
        const float m = mask[nbase * NNBR + f];
        const float dx = coords[nbr * 3 + 0] - coords[n * 3 + 0];
        const float dy = coords[nbr * 3 + 1] - coords[n * 3 + 1];
        const float dz = coords[nbr * 3 + 2] - coords[n * 3 + 2];
        rs[f] = sqrtf(dx * dx + dy * dy + dz * dz + 1e-12f);
        nb16[f] = (unsigned short)nbr;
        mv16[f] = (_Float16)m;
    }
    __syncthreads();   // Wf + rs/nb16/mv16 cross-wave

    // ---- Phase B: wave wv handles points 4wv..4wv+3, one MFMA each.
    // A[m=i=t][k=8q+j] = xT[nbr][t]*mask ; B[k][n=b=t] = exp(-10(r-c_t)^2)
    const float cb = centers[t];
    const int pbase = wv * 4;
    #pragma unroll
    for (int q = 0; q < 4; ++q) {
        const int pq = pbase + q;
        const int kb = pq * NNBR + 8 * quad;   // group-broadcast reads
        const float4 r0 = *(const float4*)&rs[kb];
        const float4 r1 = *(const float4*)&rs[kb + 4];
        const ushort8 nbv = *(const ushort8*)&nb16[kb];
        const half8 mvv = *(const half8*)&mv16[kb];
        const float rj[8] = {r0.x, r0.y, r0.z, r0.w, r1.x, r1.y, r1.z, r1.w};
        half8 af, bf;
        #pragma unroll
        for (int j = 0; j < 8; ++j) {
            const float d = rj[j] - cb;
            bf[j] = (_Float16)__expf(-10.0f * d * d);
            const float x = xT[(int)nbv[j] * CIN + t];  // 64 B line per group
            af[j] = (_Float16)(x * (float)mvv[j]);
        }
        floatx4 c = {0.0f, 0.0f, 0.0f, 0.0f};
        c = __builtin_amdgcn_mfma_f32_16x16x32_f16(af, bf, c, 0, 0, 0);
        // D[row=i=4quad+v][col=b=t] -> Mld[pq][bi = t*16 + 4quad + v], one b64
        _Float16 h[4];
        #pragma unroll
        for (int v = 0; v < 4; ++v) h[v] = (_Float16)c[v];
        *(uint2*)&Mld[pq * ML_PS + t * 16 + 4 * quad] = *(uint2*)h;
    }
    __syncthreads();   // Mld cross-wave (C reads all 16 points)

    // ---- Phase C (every wave, redundant): Out = W(16x256) * Mflat(256x16).
    // A[m=o=t][k-chunk], B[k-chunk][n=pt=t]; 8 chained MFMAs.
    floatx4 acc = {0.0f, 0.0f, 0.0f, 0.0f};
    #pragma unroll
    for (int cch = 0; cch < 8; ++cch) {
        const int bi = cch * 32 + 8 * quad;
        const half8 a = *(const half8*)&Wf[t * WF_OS + bi];
        const half8 b = *(const half8*)&Mld[t * ML_PS + bi];
        acc = __builtin_amdgcn_mfma_f32_16x16x32_f16(a, b, acc, 0, 0, 0);
    }
    // D[row=o=4quad+v][col=pt=t]; wave wv stores columns 4wv..4wv+3.
    if (wv == (t >> 2)) {
        #pragma unroll
        for (int v = 0; v < 4; ++v)
            out[(4 * quad + v) * NPTS + nbase + t] = acc[v];
    }
}

extern "C" void kernel_launch(void* const* d_in, const int* in_sizes, int n_in,
                              void* d_out, int out_size, void* d_ws, size_t ws_size,
                              hipStream_t stream) {
    const float* input   = (const float*)d_in[0];
    const float* coords  = (const float*)d_in[1];
    const float* W       = (const float*)d_in[2];
    const float* centers = (const float*)d_in[3];
    const float* mask    = (const float*)d_in[4];
    const int*   nbr     = (const int*)d_in[5];
    float* out = (float*)d_out;

    float* xT = (float*)d_ws;   // 1 MB of the 256 MB workspace
    transpose_kernel<<<NPTS / 256, 256, 0, stream>>>(input, xT);
    se3_conv_kernel<<<NPTS / 16, 256, 0, stream>>>(xT, coords, W, centers,
                                                   mask, nbr, out);
}